// Round 11
// baseline (1419.238 us; speedup 1.0000x reference)
//
#include <hip/hip_runtime.h>
#include <stdint.h>

// ---------------------------------------------------------------------------
// ST-LSTM on MI355X.  R11 = R10 skeleton + SENTINEL detection (cheap polls).
//  K3 k_recur: 64 roles from 128 blocks (bid%8<4): r=bid%8, c=bid>>3.
//   9 waves: 8 compute + 1 store. Compute waves issue ONLY L2-class vmem:
//   poll = 1 dword/wave/pass on the r-group's 64B sentinel line (sc0), then
//   bulk-read h ONCE (sc0), cvt->LDS, MFMA, gates (G from LDS), publish h
//   (plain store) -> vmcnt(0) -> B3 -> tid0 stores sentinel t+1 (plain).
//   Same-L2 ordering: h acks (write-through to XCD L2) precede sentinel.
//   Store wave: G prefetch->LDS dbuf, outH/last writes, distress scan /16.
//   Fallback: stuck wave (>1024 passes) republishes BOTH generation words
//   (pub_hist, same-thread same-address => ordered) + sentinel via agent,
//   sets distress; mutual trips converge to all-agent mode (R2-like).
//
// ws layout (bytes), total need = 126,091,776 (~120.2 MiB):
#define A_CAT_OFF  0ull                  // 16384*3072
#define WCT_OFF    50331648ull           // 2048*3072
#define WHR_OFF    56623104ull           // 2048*1024 (linear)
#define G_OFF      58720256ull           // 16384*2048*2 [t][b][dim*4+gate]
#define HBUF_OFF   125829120ull          // 2 bufs x 64 batches x 512 f32
#define DIST_OFF   126091264ull          // 4 r-groups x 64B distress lines
#define SENT_OFF   126091520ull          // 4 r-groups x 64B sentinel lines
#define WS_NEED    126091776ull

typedef short bf16x8 __attribute__((ext_vector_type(8)));
typedef float f32x4  __attribute__((ext_vector_type(4)));
typedef uint32_t u32x4 __attribute__((ext_vector_type(4)));

__device__ __forceinline__ unsigned short f2bf(float f) {
  union { float f; uint32_t u; } v; v.f = f;
  uint32_t u = v.u;
  u += 0x7FFFu + ((u >> 16) & 1u);   // RNE
  return (unsigned short)(u >> 16);
}
__device__ __forceinline__ float bf2f(unsigned short h) {
  union { uint32_t u; float f; } v; v.u = ((uint32_t)h) << 16;
  return v.f;
}
__device__ __forceinline__ float u2f(uint32_t u) {
  union { uint32_t u; float f; } v; v.u = u; return v.f;
}
__device__ __forceinline__ uint32_t f2u(float f) {
  union { float f; uint32_t u; } v; v.f = f; return v.u;
}
__device__ __forceinline__ float fsigmoid(float x) { return 1.0f / (1.0f + __expf(-x)); }
__device__ __forceinline__ float ftanh(float x) {
  float e = __expf(2.0f * x);
  return 1.0f - 2.0f / (e + 1.0f);
}
__device__ __forceinline__ uint4 pack8(const unsigned short* v) {
  uint4 r;
  r.x = (uint32_t)v[0] | ((uint32_t)v[1] << 16);
  r.y = (uint32_t)v[2] | ((uint32_t)v[3] << 16);
  r.z = (uint32_t)v[4] | ((uint32_t)v[5] << 16);
  r.w = (uint32_t)v[6] | ((uint32_t)v[7] << 16);
  return r;
}
__device__ __forceinline__ uint32_t pk2(uint32_t a, uint32_t b) {
  return (uint32_t)f2bf(u2f(a)) | ((uint32_t)f2bf(u2f(b)) << 16);
}

#define GLOAD_LDS16(GP, LP)                                                   \
  __builtin_amdgcn_global_load_lds(                                          \
      (const __attribute__((address_space(1))) uint32_t*)(GP),               \
      (__attribute__((address_space(3))) uint32_t*)(LP), 16, 0, 0)

// LDS-only barrier (no vmcnt drain)
#define BAR_LDS()                                                             \
  do {                                                                        \
    asm volatile("s_waitcnt lgkmcnt(0)" ::: "memory");                        \
    __builtin_amdgcn_sched_barrier(0);                                        \
    __builtin_amdgcn_s_barrier();                                             \
  } while (0)

// ---------------------------------------------------------------------- K0
__global__ __launch_bounds__(256) void k_prep(
    const float* __restrict__ Wi, const float* __restrict__ Wt,
    const float* __restrict__ Ws, const float* __restrict__ Wh,
    uint8_t* ws) {
  int id = blockIdx.x * 256 + threadIdx.x;
  if (id < 393216) {                       // W_catT: 2048 cols x 192 k-chunks
    int n  = id & 2047;
    int k0 = (id >> 11) << 3;
    unsigned short v[8];
#pragma unroll
    for (int j = 0; j < 8; ++j) {
      int k = k0 + j;
      float x;
      if (k < 512)       x = Wi[k * 2048 + n];
      else if (k < 1024) x = (n < 1536) ? Wt[(k - 512) * 1536 + n] : 0.0f;
      else               x = (n < 1536) ? Ws[(k - 1024) * 1536 + n] : 0.0f;
      v[j] = f2bf(x);
    }
    size_t off = WCT_OFF + (size_t)n * 3072 +
                 (size_t)(((uint32_t)k0 * 2u) ^ (((uint32_t)n & 7u) << 4));
    *(uint4*)(ws + off) = pack8(v);
  } else if (id < 524288) {                // Wh_rearr: LINEAR (reg-consumed)
    int id2 = id - 393216;
    int cc  = id2 & 2047;
    int k0  = (id2 >> 11) << 3;
    int col = ((cc >> 5) & 3) * 512 + (cc >> 7) * 32 + (cc & 31);
    unsigned short v[8];
#pragma unroll
    for (int j = 0; j < 8; ++j) v[j] = f2bf(Wh[(size_t)(k0 + j) * 2048 + col]);
    *(uint4*)(ws + WHR_OFF + (size_t)cc * 1024 + (size_t)k0 * 2) = pack8(v);
  } else if (id < 532480) {                // h buf0 = h_0 = 0.0f
    uint4 z; z.x = z.y = z.z = z.w = 0u;
    *(uint4*)(ws + HBUF_OFF + (size_t)(id - 524288) * 16) = z;
  } else if (id < 532512) {                // distress + sentinels = 0
    uint4 z; z.x = z.y = z.z = z.w = 0u;
    *(uint4*)(ws + DIST_OFF + (size_t)(id - 532480) * 16) = z;
  }
}

// ---------------------------------------------------------------------- K1
__global__ __launch_bounds__(192) void k_gather(
    const int* __restrict__ loc, const int* __restrict__ tdu,
    const int* __restrict__ tdl, const int* __restrict__ sdu,
    const int* __restrict__ sdl,
    const float* __restrict__ loc_emb, const float* __restrict__ tup,
    const float* __restrict__ tlo, const float* __restrict__ sup,
    const float* __restrict__ slo, uint8_t* ws) {
  int m  = blockIdx.x;        // row = b*256 + t
  int t  = m & 255;
  int k0 = threadIdx.x << 3;  // 192 chunks of 8
  float vals[8];
  if (k0 < 512) {
    const float* s = loc_emb + (size_t)loc[m] * 512 + k0;
#pragma unroll
    for (int j = 0; j < 8; ++j) vals[j] = s[j];
  } else if (k0 < 1024) {
    int e = k0 - 512;
    const float* a = tup + (size_t)tdu[m] * 512 + e;
    const float* b = tlo + (size_t)tdl[m] * 512 + e;
    float sc = (t > 0) ? (1.0f / 3600.0f) : 0.0f;
#pragma unroll
    for (int j = 0; j < 8; ++j) vals[j] = (a[j] + b[j]) * sc;
  } else {
    int e = k0 - 1024;
    const float* a = sup + (size_t)sdu[m] * 512 + e;
    const float* b = slo + (size_t)sdl[m] * 512 + e;
    float sc = (t > 0) ? (1.0f / 1000.0f) : 0.0f;
#pragma unroll
    for (int j = 0; j < 8; ++j) vals[j] = (a[j] + b[j]) * sc;
  }
  unsigned short v[8];
#pragma unroll
  for (int j = 0; j < 8; ++j) v[j] = f2bf(vals[j]);
  size_t off = A_CAT_OFF + (size_t)m * 3072 +
               (size_t)(((uint32_t)k0 * 2u) ^ (((uint32_t)m & 7u) << 4));
  *(uint4*)(ws + off) = pack8(v);
}

// ---------------------------------------------------------------------- K2
__global__ __launch_bounds__(256) void k_gemm(uint8_t* ws,
                                              const float* __restrict__ bi) {
  __shared__ uint8_t A_lds[16384];   // 128 rows x 64 k bf16 (swizzled content)
  __shared__ uint8_t B_lds[16384];   // 128 cols x 64 k bf16
  const uint8_t* Acat = ws + A_CAT_OFF;
  const uint8_t* Wct  = ws + WCT_OFF;
  uint8_t* Gp = ws + G_OFF;
  int tid = threadIdx.x;
  int lane = tid & 63, wave = tid >> 6;
  int wm = wave >> 1, wn = wave & 1;
  int tile_m = blockIdx.x >> 4, tile_n = blockIdx.x & 15;

  f32x4 acc[4][4];
#pragma unroll
  for (int m = 0; m < 4; ++m)
#pragma unroll
    for (int n = 0; n < 4; ++n) acc[m][n] = f32x4{0.f, 0.f, 0.f, 0.f};

  for (int kb = 0; kb < 1536; kb += 64) {
#pragma unroll
    for (int i = 0; i < 4; ++i) {
      int lidx = i * 256 + tid;
      int row = lidx >> 3, ch = lidx & 7;
      GLOAD_LDS16(Acat + (size_t)(tile_m * 128 + row) * 3072 + kb * 2 + ch * 16,
                  A_lds + (i * 256 + wave * 64) * 16);
    }
#pragma unroll
    for (int i = 0; i < 4; ++i) {
      int lidx = i * 256 + tid;
      int row = lidx >> 3, ch = lidx & 7;
      GLOAD_LDS16(Wct + (size_t)(tile_n * 128 + row) * 3072 + kb * 2 + ch * 16,
                  B_lds + (i * 256 + wave * 64) * 16);
    }
    __syncthreads();
#pragma unroll
    for (int kk = 0; kk < 2; ++kk) {
      int koff = kk * 64 + ((lane >> 4) << 4);
      bf16x8 af[4], bfr[4];
#pragma unroll
      for (int m = 0; m < 4; ++m) {
        int row = wm * 64 + m * 16 + (lane & 15);
        af[m] = *(const bf16x8*)(A_lds + row * 128 + (koff ^ ((row & 7) << 4)));
      }
#pragma unroll
      for (int n = 0; n < 4; ++n) {
        int row = wn * 64 + n * 16 + (lane & 15);
        bfr[n] = *(const bf16x8*)(B_lds + row * 128 + (koff ^ ((row & 7) << 4)));
      }
#pragma unroll
      for (int m = 0; m < 4; ++m)
#pragma unroll
        for (int n = 0; n < 4; ++n)
          acc[m][n] = __builtin_amdgcn_mfma_f32_16x16x32_bf16(af[m], bfr[n],
                                                              acc[m][n], 0, 0, 0);
    }
    __syncthreads();
  }
  // epilogue: + bias, bf16, scatter to G laid out [t][b][dim*4 + gate]
  int lr = lane >> 4, lc = lane & 15;
#pragma unroll
  for (int n = 0; n < 4; ++n) {
    int gcol = tile_n * 128 + wn * 64 + n * 16 + lc;
    float bv = bi[gcol];
    int gidx = (gcol & 511) * 4 + (gcol >> 9);     // dim*4 + gate
#pragma unroll
    for (int m = 0; m < 4; ++m) {
      int growb = tile_m * 128 + wm * 64 + m * 16 + lr * 4;
#pragma unroll
      for (int q = 0; q < 4; ++q) {
        int grow = growb + q;                      // = b*256 + t
        float v = acc[m][n][q] + bv;
        size_t gi = ((size_t)(grow & 255) * 64 + (size_t)(grow >> 8)) * 2048 + gidx;
        *(unsigned short*)(Gp + gi * 2) = f2bf(v);
      }
    }
  }
}

// ---------------------------------------------------------------------- K3
// 128 blocks x 576 threads (8 compute + 1 store wave), active iff bid%8<4.
__global__ __launch_bounds__(576, 1) void k_recur(uint8_t* ws,
                                                  const int* __restrict__ vlen,
                                                  float* __restrict__ out) {
  int bid = blockIdx.x;
  if ((bid & 7) >= 4) return;
  int r = bid & 7, c = bid >> 3;

  extern __shared__ uint8_t smem[];
  uint8_t* h_lds   = smem;                     // [16][512] bf16 perm, 16384 B
  float*   tmp     = (float*)(smem + 16384);   // [16][132] f32, 8448 B
  uint8_t* g_lds   = smem + 24832;             // 2 x [16][128cols] bf16, 8192 B
  float*   pub_lds = (float*)(smem + 33024);   // 2 x 512 f32, 4096 B
  float*   c_lds   = (float*)(smem + 37120);   // 2 x 512 f32, 4096 B
  volatile uint32_t* fbl = (volatile uint32_t*)(smem + 41216);  // fb flag

  int tid = threadIdx.x;
  int lane = tid & 63, wave = tid >> 6;
  if (tid == 0) fbl[0] = 0;

  const uint8_t* Gp = ws + G_OFF;
  uint8_t* hbuf = ws + HBUF_OFF;
  uint32_t* dist = (uint32_t*)(ws + DIST_OFF + (size_t)r * 64);
  uint32_t* sent = (uint32_t*)(ws + SENT_OFF + (size_t)r * 64);

  float* outH  = out;
  float* outLH = out + 8388608;
  float* outLC = out + 8421376;

  // ---- per-role constants
  bf16x8 Bfrag[16];
  int gb = tid >> 5, d = tid & 31;   // compute: gate mapping
  int gbatch = r * 16 + gb;
  int hb_b = 2 * wave + (lane >> 5); // compute: bulk-read batch row
  int w0 = lane & 31;                // compute: bulk-read 64B slice
  float cr = 0.0f;
  bool fb = false;
  uint32_t ph0 = 0, ph1 = 0;         // published-word history (buf0/buf1)
  uint32_t sent_prev = 0;
  uint32_t* pubA = (uint32_t*)(hbuf + (size_t)gbatch * 2048 + (size_t)(c * 32 + d) * 4);
  uint32_t* pubB = (uint32_t*)((uint8_t*)pubA + 131072);
  uint32_t* sent_self = sent + c;

  int b8 = lane >> 2, seg = lane & 3;            // store wave mapping
  int w8b = r * 16 + b8;
  int w8vl = 0;
  uint4 gr0, gr1, gr2, gr3;

  if (wave < 8) {
    int cc = c * 128 + wave * 16 + (lane & 15);
    const uint8_t* wb = ws + WHR_OFF + (size_t)cc * 1024 + ((lane >> 4) << 4);
#pragma unroll
    for (int kk = 0; kk < 16; ++kk)
      Bfrag[kk] = *(const bf16x8*)(wb + kk * 64);
  } else {
    w8vl = vlen[w8b];
    const uint8_t* gp0 = Gp + (size_t)w8b * 4096 + (size_t)c * 256 + (size_t)seg * 64;
    uint4 a0 = *(const uint4*)(gp0);
    uint4 a1 = *(const uint4*)(gp0 + 16);
    uint4 a2 = *(const uint4*)(gp0 + 32);
    uint4 a3 = *(const uint4*)(gp0 + 48);
    uint8_t* gl = g_lds + b8 * 256 + seg * 64;
    *(uint4*)(gl)      = a0;
    *(uint4*)(gl + 16) = a1;
    *(uint4*)(gl + 32) = a2;
    *(uint4*)(gl + 48) = a3;
    const uint8_t* gp1 = gp0 + 262144;
    gr0 = *(const uint4*)(gp1);
    gr1 = *(const uint4*)(gp1 + 16);
    gr2 = *(const uint4*)(gp1 + 32);
    gr3 = *(const uint4*)(gp1 + 48);
  }

  __syncthreads();   // startup only

  for (int t = 0; t < 256; ++t) {
    uint8_t* mybuf = hbuf + (size_t)(t & 1) * 131072;   // holds h_t
    if (wave < 8) {
      // ---- remote-distress adoption (LDS flag set by store wave)
      if (!fb && fbl[0] != 0) {
        fb = true;
        __hip_atomic_store(pubA, ph0, __ATOMIC_RELAXED, __HIP_MEMORY_SCOPE_AGENT);
        __hip_atomic_store(pubB, ph1, __ATOMIC_RELAXED, __HIP_MEMORY_SCOPE_AGENT);
        if (tid == 0)
          __hip_atomic_store(sent_self, sent_prev, __ATOMIC_RELAXED,
                             __HIP_MEMORY_SCOPE_AGENT);
      }
      // ---- poll sentinel line: all sent[r][*] >= t (1 dword/wave/pass)
      {
        const uint32_t* sp = sent + (lane & 15);
        int passes = 0;
        for (;;) {
          uint32_t sv;
          if (!fb) {
            asm volatile("global_load_dword %0, %1, off sc0\n\t"
                         "s_waitcnt vmcnt(0)"
                         : "=v"(sv) : "v"(sp) : "memory");
            __builtin_amdgcn_sched_barrier(0);
          } else {
            sv = __hip_atomic_load(sp, __ATOMIC_RELAXED, __HIP_MEMORY_SCOPE_AGENT);
          }
          if (__ballot(sv < (uint32_t)t) == 0ULL) break;
          if (++passes > 1024) {       // stuck: degrade + republish history
            passes = 512;
            if (!fb) {
              fb = true;
              if (lane == 0)
                __hip_atomic_store(dist, 1u, __ATOMIC_RELAXED,
                                   __HIP_MEMORY_SCOPE_AGENT);
              fbl[0] = 1;
              __hip_atomic_store(pubA, ph0, __ATOMIC_RELAXED, __HIP_MEMORY_SCOPE_AGENT);
              __hip_atomic_store(pubB, ph1, __ATOMIC_RELAXED, __HIP_MEMORY_SCOPE_AGENT);
              if (tid == 0)
                __hip_atomic_store(sent_self, sent_prev, __ATOMIC_RELAXED,
                                   __HIP_MEMORY_SCOPE_AGENT);
            }
          }
        }
      }
      // ---- bulk-read h_t ONCE (validity guaranteed by sentinel ordering)
      u32x4 x0, x1, x2, x3;
      {
        const uint8_t* hb = mybuf + (size_t)r * 32768 +
                            (size_t)hb_b * 2048 + (size_t)w0 * 64;
        if (!fb) {
          asm volatile(
            "global_load_dwordx4 %0, %4, off sc0\n\t"
            "global_load_dwordx4 %1, %5, off sc0\n\t"
            "global_load_dwordx4 %2, %6, off sc0\n\t"
            "global_load_dwordx4 %3, %7, off sc0\n\t"
            "s_waitcnt vmcnt(0)"
            : "=v"(x0), "=v"(x1), "=v"(x2), "=v"(x3)
            : "v"(hb), "v"(hb + 16), "v"(hb + 32), "v"(hb + 48)
            : "memory");
          __builtin_amdgcn_sched_barrier(0);
        } else {
          uint64_t y[8];
#pragma unroll
          for (int i = 0; i < 8; ++i)
            y[i] = __hip_atomic_load((const uint64_t*)(hb + i * 8),
                                     __ATOMIC_RELAXED, __HIP_MEMORY_SCOPE_AGENT);
          x0 = u32x4{(uint32_t)y[0], (uint32_t)(y[0] >> 32), (uint32_t)y[1], (uint32_t)(y[1] >> 32)};
          x1 = u32x4{(uint32_t)y[2], (uint32_t)(y[2] >> 32), (uint32_t)y[3], (uint32_t)(y[3] >> 32)};
          x2 = u32x4{(uint32_t)y[4], (uint32_t)(y[4] >> 32), (uint32_t)y[5], (uint32_t)(y[5] >> 32)};
          x3 = u32x4{(uint32_t)y[6], (uint32_t)(y[6] >> 32), (uint32_t)y[7], (uint32_t)(y[7] >> 32)};
        }
      }
      // ---- cvt f32->bf16, write permuted h_lds (R9/R10-verified layout)
      {
        uint4 v0, v1;
        v0.x = pk2(x0[0], x0[1]); v0.y = pk2(x0[2], x0[3]);
        v0.z = pk2(x1[0], x1[1]); v0.w = pk2(x1[2], x1[3]);
        v1.x = pk2(x2[0], x2[1]); v1.y = pk2(x2[2], x2[3]);
        v1.z = pk2(x3[0], x3[1]); v1.w = pk2(x3[2], x3[3]);
        int s = hb_b & 7;
        int c0 = (2 * w0) ^ (w0 >> 2) ^ s;
        int c1 = c0 ^ 1;
        *(uint4*)(h_lds + hb_b * 1024 + c0 * 16) = v0;
        *(uint4*)(h_lds + hb_b * 1024 + c1 * 16) = v1;
      }
    } else {
      // ---- store wave: publish G(t+1) to LDS, outputs for t-1, prefetch
      asm volatile("s_waitcnt vmcnt(0)" ::: "memory");
      __builtin_amdgcn_sched_barrier(0);
      {
        uint8_t* gl = g_lds + ((t + 1) & 1) * 4096 + b8 * 256 + seg * 64;
        *(uint4*)(gl)      = gr0;
        *(uint4*)(gl + 16) = gr1;
        *(uint4*)(gl + 32) = gr2;
        *(uint4*)(gl + 48) = gr3;
      }
      if (t > 0) {
        const float* pl = pub_lds + ((t + 1) & 1) * 512 + b8 * 32 + seg * 8;
        float4 h0 = *(const float4*)pl;
        float4 h1 = *(const float4*)(pl + 4);
        float* oh = outH + ((size_t)w8b * 256 + (size_t)(t - 1)) * 512 +
                    (size_t)(c * 32 + seg * 8);
        *(float4*)oh = h0;
        *(float4*)(oh + 4) = h1;
        if (t - 1 == w8vl - 1) {
          const float* cl = c_lds + ((t + 1) & 1) * 512 + b8 * 32 + seg * 8;
          float4 cv0 = *(const float4*)cl;
          float4 cv1 = *(const float4*)(cl + 4);
          size_t lb = (size_t)w8b * 512 + (size_t)(c * 32 + seg * 8);
          *(float4*)(outLH + lb) = h0;
          *(float4*)(outLH + lb + 4) = h1;
          *(float4*)(outLC + lb) = cv0;
          *(float4*)(outLC + lb + 4) = cv1;
        }
      }
      {  // issue G(t+2) loads
        const uint8_t* gp = Gp + (size_t)(((t + 2) & 255) * 64 + w8b) * 4096 +
                            (size_t)c * 256 + (size_t)seg * 64;
        gr0 = *(const uint4*)(gp);
        gr1 = *(const uint4*)(gp + 16);
        gr2 = *(const uint4*)(gp + 32);
        gr3 = *(const uint4*)(gp + 48);
      }
      // ---- distress scan every 16 steps (acks drain next step, off
      //      compute-wave paths; mutual->1024 trips guarantee liveness anyway)
      if ((t & 15) == 0 && lane == 0) {
        uint32_t dv = __hip_atomic_load(dist, __ATOMIC_RELAXED,
                                        __HIP_MEMORY_SCOPE_AGENT);
        if (dv != 0) fbl[0] = 1;
      }
    }
    BAR_LDS();                                     // B1

    if (wave < 8) {
      // ---- MFMA: tmp(16 x wave's 16 cols) = h(16x512) @ Wh_regs
      f32x4 acc0 = f32x4{0.f, 0.f, 0.f, 0.f}, acc1 = acc0;
      {
        int lrow = lane & 15;
        int g = lane >> 4;
        int gs = (g ^ (lrow & 7)) * 16;
#pragma unroll
        for (int kk = 0; kk < 16; kk += 2) {
          int k0c = ((kk * 4) ^ (kk >> 1)) * 16;
          int k1c = (((kk + 1) * 4) ^ ((kk + 1) >> 1)) * 16;
          bf16x8 a0 = *(const bf16x8*)(h_lds + lrow * 1024 + (k0c ^ gs));
          bf16x8 a1 = *(const bf16x8*)(h_lds + lrow * 1024 + (k1c ^ gs));
          acc0 = __builtin_amdgcn_mfma_f32_16x16x32_bf16(a0, Bfrag[kk], acc0, 0, 0, 0);
          acc1 = __builtin_amdgcn_mfma_f32_16x16x32_bf16(a1, Bfrag[kk + 1], acc1, 0, 0, 0);
        }
      }
      {
        int colb = wave * 16 + (lane & 15);
        int rowd = (lane >> 4) << 2;
#pragma unroll
        for (int q = 0; q < 4; ++q)
          tmp[(rowd + q) * 132 + colb] = acc0[q] + acc1[q];
      }
    }
    BAR_LDS();                                     // B2

    if (wave < 8) {
      // ---- gates (G from LDS)
      float hval, cval;
      {
        uint64_t gx = *(const uint64_t*)(g_lds + (t & 1) * 4096 + gb * 256 + d * 8);
        int tb = gb * 132 + d;
        float ip = tmp[tb]      + bf2f((unsigned short)(gx & 0xFFFF));
        float fp = tmp[tb + 32] + bf2f((unsigned short)((gx >> 16) & 0xFFFF));
        float op = tmp[tb + 64] + bf2f((unsigned short)((gx >> 32) & 0xFFFF));
        float gp = tmp[tb + 96] + bf2f((unsigned short)((gx >> 48) & 0xFFFF));
        float ig = fsigmoid(ip), fg = fsigmoid(fp), og = fsigmoid(op);
        float gt = ftanh(gp);
        cval = fg * cr + ig * gt;
        cr = cval;
        hval = og * ftanh(cval);
      }
      // ---- publish h_{t+1} (plain L2 store) + flush (L2 acks only)
      {
        uint32_t pubw = f2u(hval);
        uint32_t* pub = (((t + 1) & 1) == 0) ? pubA : pubB;
        asm volatile("global_store_dword %0, %1, off" :: "v"(pub), "v"(pubw) : "memory");
        if (fb)
          __hip_atomic_store(pub, pubw, __ATOMIC_RELAXED, __HIP_MEMORY_SCOPE_AGENT);
        if (((t + 1) & 1) == 0) ph0 = pubw; else ph1 = pubw;
        pub_lds[(t & 1) * 512 + tid] = hval;
        c_lds[(t & 1) * 512 + tid] = cval;
        asm volatile("s_waitcnt vmcnt(0)" ::: "memory");   // h acks in L2
        __builtin_amdgcn_sched_barrier(0);
      }
    }
    BAR_LDS();                                     // B3 (all waves' h ack'd)
    if (wave < 8 && tid == 0) {
      uint32_t sval = (uint32_t)(t + 1);
      asm volatile("global_store_dword %0, %1, off" :: "v"(sent_self), "v"(sval) : "memory");
      if (fb)
        __hip_atomic_store(sent_self, sval, __ATOMIC_RELAXED, __HIP_MEMORY_SCOPE_AGENT);
      sent_prev = sval;
    }
  }
  // ---- epilogue (store wave): row 255 outputs
  if (wave == 8) {
    const float* pl = pub_lds + 512 + b8 * 32 + seg * 8;
    float4 h0 = *(const float4*)pl;
    float4 h1 = *(const float4*)(pl + 4);
    float* oh = outH + ((size_t)w8b * 256 + 255) * 512 + (size_t)(c * 32 + seg * 8);
    *(float4*)oh = h0;
    *(float4*)(oh + 4) = h1;
    if (w8vl == 256) {
      const float* cl = c_lds + 512 + b8 * 32 + seg * 8;
      float4 cv0 = *(const float4*)cl;
      float4 cv1 = *(const float4*)(cl + 4);
      size_t lb = (size_t)w8b * 512 + (size_t)(c * 32 + seg * 8);
      *(float4*)(outLH + lb) = h0;
      *(float4*)(outLH + lb + 4) = h1;
      *(float4*)(outLC + lb) = cv0;
      *(float4*)(outLC + lb + 4) = cv1;
    }
  }
}

// ---------------------------------------------------------------------------
extern "C" void kernel_launch(void* const* d_in, const int* in_sizes, int n_in,
                              void* d_out, int out_size, void* d_ws, size_t ws_size,
                              hipStream_t stream) {
  const int*   loc     = (const int*)d_in[0];
  const int*   tdu     = (const int*)d_in[1];
  const int*   tdl     = (const int*)d_in[2];
  const int*   sdu     = (const int*)d_in[3];
  const int*   sdl     = (const int*)d_in[4];
  const int*   vlen    = (const int*)d_in[5];
  const float* loc_emb = (const float*)d_in[6];
  const float* tup     = (const float*)d_in[7];
  const float* tlo     = (const float*)d_in[8];
  const float* sup     = (const float*)d_in[9];
  const float* slo     = (const float*)d_in[10];
  const float* Wt      = (const float*)d_in[11];
  const float* Ws      = (const float*)d_in[12];
  const float* Wi      = (const float*)d_in[13];
  const float* bi      = (const float*)d_in[14];
  const float* Wh      = (const float*)d_in[15];
  uint8_t* ws = (uint8_t*)d_ws;
  float* out = (float*)d_out;

  if (ws_size < WS_NEED) return;  // need ~120.2 MiB scratch

  (void)hipFuncSetAttribute((const void*)k_recur,
                            hipFuncAttributeMaxDynamicSharedMemorySize, 98304);

  k_prep  <<<2081, 256, 0, stream>>>(Wi, Wt, Ws, Wh, ws);
  k_gather<<<16384, 192, 0, stream>>>(loc, tdu, tdl, sdu, sdl,
                                      loc_emb, tup, tlo, sup, slo, ws);
  k_gemm  <<<2048, 256, 0, stream>>>(ws, bi);
  k_recur <<<128, 576, 98304, stream>>>(ws, vlen, out);
}